// Round 4
// baseline (14663.542 us; speedup 1.0000x reference)
//
#include <hip/hip_runtime.h>
#include <math.h>
#include <stdint.h>

// ---------------------------------------------------------------------------
// Speller decoder, persistent kernel, 512 blocks x 256 threads, 3 device
// barriers per step. R4:
//  - XCD pinning: b = blk&31 -> all 16 t-chunk blocks of batch b on XCD b%8;
//    LF converted once to bf16 (4 MB per XCD = L2-resident attention stream).
//  - P3 eliminated: the P2 per-batch merge block computes hid itself
//    (h + ctx already in LDS; Wp via plain cached read-only loads).
//  - P4 merge publishes tok only; P1 reads Emb[tok] via plain cached loads.
// Cross-block mutable data still moves via relaxed AGENT atomics (sc0 sc1,
// L3-coherent, no cache-maintenance ops anywhere).
// ---------------------------------------------------------------------------

#define NB 512
#define NT 256

constexpr int Tv = 1024, Vv = 5000, STEPS = 64;

// ---- u32 counter region (monotonic, zeroed by init) ----
constexpr int MCNT = 0;
constexpr int GEN  = 16;
constexpr int GCNT = 64;              // 32 group counters, stride 16
constexpr int GFLG = 1024;            // 32 group release flags, stride 32
constexpr int ACNT = 2048;            // 32 attn-merge counters, stride 16
constexpr int LCNT = 2560;            // 32 logits-merge counters, stride 16
constexpr int WSU  = 4096;

// ---- float region offsets (wsf = (float*)ws + WSU) ----
constexpr int XH   = 0;                    // [32][512] ctx
constexpr int HB   = XH + 32*512;          // [2][32][512] h double-buffer
constexpr int HID  = HB + 2*32*512;        // [32][512]
constexpr int PART = HID + 32*512;         // [32][4][16][130] attn partials
constexpr int E3   = PART + 32*4*16*130;   // [32][1024] head-3 energies
constexpr int PM   = E3 + 32*1024;         // [32][256]
constexpr int PSUM = PM + 32*256;          // [32][256]
constexpr int PIDX = PSUM + 32*256;        // [32][256] (int)
constexpr int MLS  = PIDX + 32*256;        // [32][2] (max, lse)
constexpr int TOK_ = MLS + 64;             // [32] int tokens
constexpr int LFH_OFF = 389248;            // bf16 LF copy (16B aligned)

__device__ __forceinline__ float sigm(float x) { return 1.f / (1.f + expf(-x)); }

// ---- coherent (L3, sc0 sc1) helpers: relaxed agent atomics ----
__device__ __forceinline__ float ld4(const float* p) {
  return __hip_atomic_load(const_cast<float*>(p), __ATOMIC_RELAXED, __HIP_MEMORY_SCOPE_AGENT);
}
__device__ __forceinline__ void st4(float* p, float v) {
  __hip_atomic_store(p, v, __ATOMIC_RELAXED, __HIP_MEMORY_SCOPE_AGENT);
}
__device__ __forceinline__ float2 ld8(const float* p) {
  unsigned long long u = __hip_atomic_load(
      reinterpret_cast<unsigned long long*>(const_cast<float*>(p)),
      __ATOMIC_RELAXED, __HIP_MEMORY_SCOPE_AGENT);
  union { unsigned long long u; float2 f; } c; c.u = u; return c.f;
}
__device__ __forceinline__ void st8(float* p, float2 v) {
  union { float2 f; unsigned long long u; } c; c.f = v;
  __hip_atomic_store(reinterpret_cast<unsigned long long*>(p), c.u,
                     __ATOMIC_RELAXED, __HIP_MEMORY_SCOPE_AGENT);
}
__device__ __forceinline__ int ld4i(const int* p) {
  return (int)__hip_atomic_load(reinterpret_cast<unsigned*>(const_cast<int*>(p)),
                                __ATOMIC_RELAXED, __HIP_MEMORY_SCOPE_AGENT);
}
__device__ __forceinline__ void st4i(int* p, int v) {
  __hip_atomic_store(reinterpret_cast<unsigned*>(p), (unsigned)v,
                     __ATOMIC_RELAXED, __HIP_MEMORY_SCOPE_AGENT);
}
__device__ __forceinline__ unsigned ld_rlx(unsigned* p) {
  return __hip_atomic_load(p, __ATOMIC_RELAXED, __HIP_MEMORY_SCOPE_AGENT);
}
__device__ __forceinline__ void st_rlx(unsigned* p, unsigned v) {
  __hip_atomic_store(p, v, __ATOMIC_RELAXED, __HIP_MEMORY_SCOPE_AGENT);
}
__device__ __forceinline__ unsigned add_rlx(unsigned* p, unsigned v) {
  return __hip_atomic_fetch_add(p, v, __ATOMIC_RELAXED, __HIP_MEMORY_SCOPE_AGENT);
}

__device__ __forceinline__ void gsync(unsigned* wsu, int blk, int tid, unsigned& myGen) {
  __syncthreads();
  if (tid == 0) {
    const unsigned target = ++myGen;
    const int grp = blk >> 4;
    unsigned o = add_rlx(&wsu[GCNT + grp*16], 1u);
    if (o == target*16u - 1u) {
      unsigned o2 = add_rlx(&wsu[MCNT], 1u);
      if (o2 == target*32u - 1u) st_rlx(&wsu[GEN], target);
    }
    if ((blk & 15) == 0) {
      while (ld_rlx(&wsu[GEN]) != target) __builtin_amdgcn_s_sleep(2);
      st_rlx(&wsu[GFLG + grp*32], target);
    } else {
      while (ld_rlx(&wsu[GFLG + grp*32]) != target) __builtin_amdgcn_s_sleep(2);
    }
  }
  __syncthreads();
}

__global__ void speller_init(const float* __restrict__ LF,
                             float* __restrict__ wsf, unsigned* __restrict__ wsu) {
  int b = blockIdx.x;
  for (int i = threadIdx.x; i < 512; i += NT) {
    st4(wsf + XH + b*512 + i, LF[(size_t)b*Tv*512 + i]);  // ctx0 = LF[b,0,:]
    st4(wsf + HB + b*512 + i, 0.f);                       // h0 (buffer 0)
  }
  if (threadIdx.x == 0) st4i((int*)(wsf + TOK_) + b, 0);
  if (b == 0) for (int i = threadIdx.x; i < WSU; i += NT) st_rlx(wsu + i, 0u);
}

__device__ __forceinline__ unsigned short f2bf(float f) {
  unsigned b = __float_as_uint(f);
  return (unsigned short)((b + 0x7fffu + ((b >> 16) & 1u)) >> 16);
}
__global__ void lf_convert(const float* __restrict__ LF, unsigned short* __restrict__ LFH) {
  size_t i = ((size_t)blockIdx.x * NT + threadIdx.x) * 8;   // 8192 blocks
  float4 a = *(const float4*)(LF + i), b = *(const float4*)(LF + i + 4);
  uint4 o;
  o.x = (unsigned)f2bf(a.x) | ((unsigned)f2bf(a.y) << 16);
  o.y = (unsigned)f2bf(a.z) | ((unsigned)f2bf(a.w) << 16);
  o.z = (unsigned)f2bf(b.x) | ((unsigned)f2bf(b.y) << 16);
  o.w = (unsigned)f2bf(b.z) | ((unsigned)f2bf(b.w) << 16);
  *(uint4*)(LFH + i) = o;
}

struct LdsA { float Wg[8][1536]; float gb[8]; };   // rows i,i,f,f,g,g,o,o of units 2j,2j+1
struct LdsB { float Wc[20][512]; float bcl[20]; };
union  LdsU { LdsA a; LdsB b; };

template <bool USEBF>
__launch_bounds__(NT, 2)
__global__ void speller_main(const float* __restrict__ LF, const unsigned short* __restrict__ LFH,
                             const float* __restrict__ Emb,
                             const float* __restrict__ Wih, const float* __restrict__ Whh,
                             const float* __restrict__ bih, const float* __restrict__ bhh,
                             const float* __restrict__ Wp,  const float* __restrict__ bp,
                             const float* __restrict__ Wc,  const float* __restrict__ bc,
                             float* __restrict__ out, unsigned* __restrict__ wsu,
                             float* __restrict__ wsf) {
  const int blk = blockIdx.x, tid = threadIdx.x;
  unsigned myGen = 0;
  __shared__ LdsU lds;
  __shared__ __align__(16) float scr[1040];
  __shared__ int sint[300];

  // ---------------- one-time LDS weight preload (plain cached) -------------
  if (blk < 256) {
    const int u0 = blk * 2;
    for (int idx = tid; idx < 8*1536; idx += NT) {
      int r = idx / 1536, k = idx - r*1536;
      int g = r >> 1, uu = r & 1, row = g*512 + u0 + uu;
      lds.a.Wg[r][k] = (k < 1024) ? Wih[(size_t)row*1024 + k]
                                  : Whh[(size_t)row*512 + (k-1024)];
    }
    if (tid < 8) {
      int g = tid >> 1, uu = tid & 1, row = g*512 + u0 + uu;
      lds.a.gb[tid] = bih[row] + bhh[row];
    }
  } else {
    const int blk2 = blk - 256, v0 = blk2*20;
    if (v0 < Vv) {
      for (int idx = tid; idx < 20*512; idx += NT) {
        int vi = idx >> 9, k = idx & 511;
        lds.b.Wc[vi][k] = Wc[(size_t)(v0+vi)*512 + k];
      }
      if (tid < 20) lds.b.bcl[tid] = bc[v0+tid];
    }
  }
  __syncthreads();

  float c_reg[2][4];
#pragma unroll
  for (int uu = 0; uu < 2; ++uu)
#pragma unroll
    for (int i = 0; i < 4; ++i) c_reg[uu][i] = 0.f;
  float lgv[20];

#pragma unroll 1
  for (int s = 0; s < STEPS; ++s) {
    const int rbuf = s & 1, wbuf = (s + 1) & 1;

    // ===== Phase 1: gates GEMV + fused LSTM (blk<256) | out-write (>=256) ==
    if (blk < 256) {
      if (tid < 32) sint[64 + tid] = ld4i((const int*)(wsf + TOK_) + tid);
      __syncthreads();
      const int u0 = blk * 2;
      const int slot = tid >> 5, ks = tid & 31, b0 = slot * 4;
      float acc[8][4];
#pragma unroll
      for (int r = 0; r < 8; ++r)
#pragma unroll
        for (int i = 0; i < 4; ++i) acc[r][i] = 0.f;
      int tokv[4];
#pragma unroll
      for (int i = 0; i < 4; ++i) tokv[i] = sint[64 + b0 + i];
      // k in [0,512): embedding rows, plain cached loads
#pragma unroll 2
      for (int q = 0; q < 4; ++q) {
        const int kq = q*32 + ks;
        float4 xv[4];
#pragma unroll
        for (int i = 0; i < 4; ++i)
          xv[i] = *(const float4*)(Emb + (size_t)tokv[i]*512 + kq*4);
#pragma unroll
        for (int r = 0; r < 8; ++r) {
          float4 wv = *(const float4*)(&lds.a.Wg[r][kq*4]);
#pragma unroll
          for (int i = 0; i < 4; ++i)
            acc[r][i] += wv.x*xv[i].x + wv.y*xv[i].y + wv.z*xv[i].z + wv.w*xv[i].w;
        }
      }
      // k in [512,1024): ctx (sc1)
#pragma unroll 2
      for (int q = 0; q < 4; ++q) {
        const int kq = q*32 + ks;
        float2 xa[4], xb[4];
#pragma unroll
        for (int i = 0; i < 4; ++i) {
          const float* p = wsf + XH + (size_t)(b0+i)*512 + kq*4;
          xa[i] = ld8(p); xb[i] = ld8(p + 2);
        }
#pragma unroll
        for (int r = 0; r < 8; ++r) {
          float4 wv = *(const float4*)(&lds.a.Wg[r][512 + kq*4]);
#pragma unroll
          for (int i = 0; i < 4; ++i)
            acc[r][i] += wv.x*xa[i].x + wv.y*xa[i].y + wv.z*xb[i].x + wv.w*xb[i].y;
        }
      }
      // k in [1024,1536): h (sc1)
#pragma unroll 2
      for (int q = 0; q < 4; ++q) {
        const int kq = q*32 + ks;
        float2 xa[4], xb[4];
#pragma unroll
        for (int i = 0; i < 4; ++i) {
          const float* p = wsf + HB + rbuf*16384 + (size_t)(b0+i)*512 + kq*4;
          xa[i] = ld8(p); xb[i] = ld8(p + 2);
        }
#pragma unroll
        for (int r = 0; r < 8; ++r) {
          float4 wv = *(const float4*)(&lds.a.Wg[r][1024 + kq*4]);
#pragma unroll
          for (int i = 0; i < 4; ++i)
            acc[r][i] += wv.x*xa[i].x + wv.y*xa[i].y + wv.z*xb[i].x + wv.w*xb[i].y;
        }
      }
#pragma unroll
      for (int r = 0; r < 8; ++r)
#pragma unroll
        for (int i = 0; i < 4; ++i) {
          float v = acc[r][i];
          v += __shfl_xor(v, 16); v += __shfl_xor(v, 8); v += __shfl_xor(v, 4);
          v += __shfl_xor(v, 2);  v += __shfl_xor(v, 1);
          acc[r][i] = v + lds.a.gb[r];
        }
      float hnew[2][4];
#pragma unroll
      for (int uu = 0; uu < 2; ++uu)
#pragma unroll
        for (int i = 0; i < 4; ++i) {
          float cn = sigm(acc[2+uu][i]) * c_reg[uu][i]
                   + sigm(acc[uu][i]) * tanhf(acc[4+uu][i]);
          c_reg[uu][i] = cn;
          hnew[uu][i] = sigm(acc[6+uu][i]) * tanhf(cn);
        }
      if (ks == 0) {
#pragma unroll
        for (int i = 0; i < 4; ++i)
          st8(wsf + HB + wbuf*16384 + (size_t)(b0+i)*512 + u0,
              make_float2(hnew[0][i], hnew[1][i]));
      }
    } else if (s > 0) {
      const int blk2 = blk - 256;
      if (blk2 < 250) {
        const int v0 = blk2 * 20, bb = tid >> 3, ks = tid & 7;
        if (ks == 0) {
          float2 ml = ld8(wsf + MLS + 2*bb);
          float sub = ml.x + ml.y;
#pragma unroll
          for (int vi = 0; vi < 20; ++vi)
            out[(size_t)(s-1)*160000 + (size_t)bb*5000 + v0 + vi] = lgv[vi] - sub;
        }
      }
    }
    gsync(wsu, blk, tid, myGen);

    // ===== Phase 2: attention (all blocks; b = blk&31 -> XCD-pinned) =======
    {
      const int b = blk & 31, tc = blk >> 5;
      float* hs = scr;  // [0,512) h ; later [512,1024) ctx (merge)
      {
        float2 hv = ld8(wsf + HB + wbuf*16384 + (size_t)b*512 + tid*2);
        hs[tid*2] = hv.x; hs[tid*2+1] = hv.y;
      }
      __syncthreads();
      const int w = tid >> 6, ln = tid & 63;
      const int t0 = tc * 64;
      float e = 0.f;
      if constexpr (USEBF) {
        const uint4* lf4 = (const uint4*)(LFH + ((size_t)(b*Tv + t0 + ln))*512 + w*128);
#pragma unroll
        for (int q = 0; q < 16; ++q) {
          uint4 v = lf4[q];
          float4 h0 = *(const float4*)(&hs[w*128 + q*8]);
          float4 h1 = *(const float4*)(&hs[w*128 + q*8 + 4]);
          e += __uint_as_float(v.x << 16) * h0.x
             + __uint_as_float(v.x & 0xffff0000u) * h0.y
             + __uint_as_float(v.y << 16) * h0.z
             + __uint_as_float(v.y & 0xffff0000u) * h0.w
             + __uint_as_float(v.z << 16) * h1.x
             + __uint_as_float(v.z & 0xffff0000u) * h1.y
             + __uint_as_float(v.w << 16) * h1.z
             + __uint_as_float(v.w & 0xffff0000u) * h1.w;
        }
      } else {
        const float4* lf4 = (const float4*)(LF + ((size_t)(b*Tv + t0 + ln))*512 + w*128);
#pragma unroll
        for (int q = 0; q < 32; ++q) {
          float4 f = lf4[q]; float4 hh = *(const float4*)(&hs[w*128 + q*4]);
          e += f.x*hh.x + f.y*hh.y + f.z*hh.z + f.w*hh.w;
        }
      }
      float m = e;
#pragma unroll
      for (int off = 32; off; off >>= 1) m = fmaxf(m, __shfl_xor(m, off));
      float p = expf(e - m);
      float l = p;
#pragma unroll
      for (int off = 32; off; off >>= 1) l += __shfl_xor(l, off);
      scr[512 + w*64 + ln] = p;
      if (w == 3) st4(wsf + E3 + (size_t)b*1024 + t0 + ln, e);
      __syncthreads();
      float c0 = 0.f, c1 = 0.f;
      if constexpr (USEBF) {
        const unsigned* lfw = (const unsigned*)LFH;
        const size_t base2 = (size_t)(b*Tv + t0)*256 + w*64 + ln;
#pragma unroll 8
        for (int i = 0; i < 64; ++i) {
          float pp = scr[512 + w*64 + i];
          unsigned u = lfw[base2 + (size_t)i*256];
          c0 += pp * __uint_as_float(u << 16);
          c1 += pp * __uint_as_float(u & 0xffff0000u);
        }
      } else {
        const float2* lf2 = (const float2*)LF;
        const size_t base2 = (size_t)(b*Tv + t0)*256 + w*64 + ln;
#pragma unroll 8
        for (int i = 0; i < 64; ++i) {
          float pp = scr[512 + w*64 + i];
          float2 f = lf2[base2 + (size_t)i*256];
          c0 += pp*f.x; c1 += pp*f.y;
        }
      }
      float* pr = wsf + PART + (size_t)((b*4 + w)*16 + tc)*130;
      st8(pr + 2 + 2*ln, make_float2(c0, c1));
      if (ln == 0) st8(pr, make_float2(m, l));
      __syncthreads();   // drains vmcnt: partials are in L3
      if (tid == 0) {
        unsigned old = add_rlx(&wsu[ACNT + b*16], 1u);
        sint[0] = (old == (unsigned)(s*16 + 15));
      }
      __syncthreads();
      if (sint[0]) {     // last arriver: merge ctx + compute hid + attn out
        const int w2 = tid >> 6, ln2 = tid & 63;
        const float* pb = wsf + PART + (size_t)(b*4 + w2)*16*130;
        float mv[16], lv[16];
        float M = -1e30f;
#pragma unroll
        for (int i = 0; i < 16; ++i) { float2 t = ld8(pb + i*130); mv[i] = t.x; lv[i] = t.y; M = fmaxf(M, t.x); }
        float L = 0.f, sc[16];
#pragma unroll
        for (int i = 0; i < 16; ++i) { sc[i] = expf(mv[i] - M); L += lv[i] * sc[i]; }
        float cc0 = 0.f, cc1 = 0.f;
#pragma unroll
        for (int i = 0; i < 16; ++i) {
          float2 cx = ld8(pb + i*130 + 2 + 2*ln2);
          cc0 += sc[i]*cx.x; cc1 += sc[i]*cx.y;
        }
        float invL = 1.f / L;
        cc0 *= invL; cc1 *= invL;
        scr[512 + w2*128 + 2*ln2] = cc0; scr[512 + w2*128 + 2*ln2 + 1] = cc1;
        st8(wsf + XH + (size_t)b*512 + w2*128 + 2*ln2, make_float2(cc0, cc1));
        if (ln2 == 0) { scr[1024 + w2*2] = M; scr[1025 + w2*2] = L; }
        __syncthreads();
        // ---- fused MLP: hid[r] = relu(Wp[r]·[h|ctx] + bp[r]) (2 rows/thr) --
#pragma unroll
        for (int rr = 0; rr < 2; ++rr) {
          const int r = tid + rr*256;
          const float4* wr = (const float4*)(Wp + (size_t)r*1024);
          float a = 0.f;
#pragma unroll 8
          for (int k4 = 0; k4 < 256; ++k4) {
            float4 wv = wr[k4];
            float4 xv = *(const float4*)(&scr[k4*4]);
            a += wv.x*xv.x + wv.y*xv.y + wv.z*xv.z + wv.w*xv.w;
          }
          st4(wsf + HID + (size_t)b*512 + r, fmaxf(a + bp[r], 0.f));
        }
        float M3 = scr[1024 + 6], iL3 = 1.f / scr[1024 + 7];
        for (int i = tid; i < 1024; i += NT)
          out[(size_t)10240000 + ((size_t)(s*32 + b))*1024 + i] =
              expf(ld4(wsf + E3 + (size_t)b*1024 + i) - M3) * iL3;
      }
    }
    gsync(wsu, blk, tid, myGen);

    // ===== Phase 4: logits + softmax/argmax partials + merge ================
    if (blk >= 256) {
      const int blk2 = blk - 256;
      if (blk2 < 250) {
        const int v0 = blk2 * 20;
        const int bb = tid >> 3, ks = tid & 7;
        float4 xr[16];
        const float* hb = wsf + HID + (size_t)bb*512;
#pragma unroll
        for (int q = 0; q < 16; ++q) {
          const float* p = hb + (q*8 + ks)*4;
          float2 a = ld8(p), b2v = ld8(p + 2);
          xr[q] = make_float4(a.x, a.y, b2v.x, b2v.y);
        }
#pragma unroll
        for (int vi = 0; vi < 20; ++vi) {
          float a = 0.f;
#pragma unroll
          for (int q = 0; q < 16; ++q) {
            float4 wv = *(const float4*)(&lds.b.Wc[vi][(q*8 + ks)*4]);
            a += wv.x*xr[q].x + wv.y*xr[q].y + wv.z*xr[q].z + wv.w*xr[q].w;
          }
          a += __shfl_xor(a, 1); a += __shfl_xor(a, 2); a += __shfl_xor(a, 4);
          lgv[vi] = a + lds.b.bcl[vi];
        }
        float mych = lgv[0]; int ami = 0;
#pragma unroll
        for (int vi = 1; vi < 20; ++vi)
          if (lgv[vi] > mych) { mych = lgv[vi]; ami = vi; }
        float sume = 0.f;
#pragma unroll
        for (int vi = 0; vi < 20; ++vi) sume += expf(lgv[vi] - mych);
        if (ks == 0) {
          st4(wsf + PM + bb*256 + blk2, mych);
          st4(wsf + PSUM + bb*256 + blk2, sume);
          st4i((int*)(wsf + PIDX) + bb*256 + blk2, v0 + ami);
        }
      }
      __syncthreads();
      if (tid < 32) {
        unsigned old = 0xffffffffu;
        if (blk2 < 250) old = add_rlx(&wsu[LCNT + tid*16], 1u);
        sint[1 + tid] = (old == (unsigned)(s*250 + 249));
      }
      __syncthreads();
      for (int b2 = 0; b2 < 32; ++b2) {
        if (sint[1 + b2]) {
          float mv = -1e30f, sv = 0.f; int iv = 0x7fffffff;
          if (tid < 250) {
            mv = ld4(wsf + PM + b2*256 + tid);
            sv = ld4(wsf + PSUM + b2*256 + tid);
            iv = ld4i((const int*)(wsf + PIDX) + b2*256 + tid);
          }
          scr[tid] = mv; sint[40 + tid] = iv;
          __syncthreads();
          for (int off = 128; off; off >>= 1) {
            if (tid < off) {
              float m2 = scr[tid + off]; int i2 = sint[40 + tid + off];
              if (m2 > scr[tid] || (m2 == scr[tid] && i2 < sint[40 + tid])) {
                scr[tid] = m2; sint[40 + tid] = i2;
              }
            }
            __syncthreads();
          }
          float M = scr[0]; int tok = sint[40];
          __syncthreads();
          scr[tid] = sv * expf(mv - M);
          __syncthreads();
          for (int off = 128; off; off >>= 1) {
            if (tid < off) scr[tid] += scr[tid + off];
            __syncthreads();
          }
          if (tid == 0) {
            st8(wsf + MLS + 2*b2, make_float2(M, logf(scr[0])));
            st4i((int*)(wsf + TOK_) + b2, tok);
          }
          __syncthreads();
        }
      }
    }
    gsync(wsu, blk, tid, myGen);
  }

  // ---------------- epilogue: step 63's log-softmax from registers ----------
  if (blk >= 256) {
    const int blk2 = blk - 256;
    if (blk2 < 250) {
      const int v0 = blk2 * 20, bb = tid >> 3, ks = tid & 7;
      if (ks == 0) {
        float2 ml = ld8(wsf + MLS + 2*bb);
        float sub = ml.x + ml.y;
#pragma unroll
        for (int vi = 0; vi < 20; ++vi)
          out[(size_t)63*160000 + (size_t)bb*5000 + v0 + vi] = lgv[vi] - sub;
      }
    }
  }
}

extern "C" void kernel_launch(void* const* d_in, const int* in_sizes, int n_in,
                              void* d_out, int out_size, void* d_ws, size_t ws_size,
                              hipStream_t stream) {
  (void)in_sizes; (void)n_in; (void)out_size;
  const float* LF  = (const float*)d_in[0];
  const float* Emb = (const float*)d_in[1];
  const float* Wih = (const float*)d_in[2];
  const float* Whh = (const float*)d_in[3];
  const float* bih = (const float*)d_in[4];
  const float* bhh = (const float*)d_in[5];
  const float* Wp  = (const float*)d_in[6];
  const float* bp  = (const float*)d_in[7];
  const float* Wc  = (const float*)d_in[8];
  const float* bc  = (const float*)d_in[9];
  float* out = (float*)d_out;
  unsigned* wsu = (unsigned*)d_ws;
  float* wsf = (float*)d_ws + WSU;
  unsigned short* LFH = (unsigned short*)(wsf + LFH_OFF);

  const size_t need = (size_t)WSU*4 + (size_t)LFH_OFF*4 + 32ull*1024*512*2;
  const bool useBf = ws_size >= need;

  speller_init<<<32, NT, 0, stream>>>(LF, wsf, wsu);
  if (useBf) {
    lf_convert<<<8192, NT, 0, stream>>>(LF, LFH);
    speller_main<true><<<NB, NT, 0, stream>>>(LF, LFH, Emb, Wih, Whh, bih, bhh,
                                              Wp, bp, Wc, bc, out, wsu, wsf);
  } else {
    speller_main<false><<<NB, NT, 0, stream>>>(LF, LFH, Emb, Wih, Whh, bih, bhh,
                                               Wp, bp, Wc, bc, out, wsu, wsf);
  }
}